// Round 13
// baseline (202.102 us; speedup 1.0000x reference)
//
#include <hip/hip_runtime.h>

// StackedGIN: L=3 layers of { agg = h + scatter_sum(h[src] -> dst);
//   h = relu( relu(agg@W1+B1) @ W2 + B2 ) }, then out = h@Wc + Bc.
// N=50000, E=800000, D=96, C=10.
//
// R1: float4 gather.  R2: wave-scan slots.  R3: bf16 MFMA MLP.
// R4: h/agg bf16.  R5: prep fuse + fused classifier.  R6: no coop launch.
// R7 FAILED: agg-in-MLP capped occupancy.  R8: u16 csr.  R9: own zero.
// R10 NEUTRAL: fill was line-ping-pong bound, not latency bound.
// R11: bucketed CSR (stride 64) + XCD-partitioned fill (g=blockIdx&7 owns
//      a dst range) -> hist/assign gone, fill ping-pong cured. 236->189us.
// R12: h stored as TWO feature-half buffers hlo/hhi (4.8MB each, ~= one
//      XCD's 4MB L2) and aggregation runs as two SEQUENTIAL passes ->
//      random gather working set L2-resident per pass (was 9.6MB, ~40% hit).
//      Same arithmetic/rounding; mlp/prep write h split per-cb.
// ws layout: hlo(N*48 bf16) | hhi(N*48 bf16) | aggbuf(N*96 bf16) |
//            cursor(N) | csr16(N*64 u16) | wt(6*9216 u16)

#define TPB 256
#define LDA 104  // bf16 elems per LDS row: 96 + 8 pad
#define BS 64    // csr bucket stride per node

typedef __attribute__((ext_vector_type(8))) short bfrag8;
typedef __attribute__((ext_vector_type(8))) unsigned short u16x8;
typedef __attribute__((ext_vector_type(4))) float f32x4;

__device__ inline unsigned short f2bf(float x) {  // RNE f32 -> bf16 bits
  unsigned int u = __float_as_uint(x);
  unsigned int r = u + 0x7FFFu + ((u >> 16) & 1u);
  return (unsigned short)(r >> 16);
}
__device__ inline float bf2f(unsigned short u) {
  return __uint_as_float(((unsigned int)u) << 16);
}

// jobs: [0,N) zero cursor; then weight transpose->bf16; then x->bf16 (split).
__global__ __launch_bounds__(TPB) void prep_kernel(
    int* __restrict__ cursor, int N,
    const float* __restrict__ W1, const float* __restrict__ W2,
    unsigned short* __restrict__ wt,
    const float4* __restrict__ x4, unsigned short* __restrict__ hlo,
    unsigned short* __restrict__ hhi, int total8) {
  int t = blockIdx.x * TPB + threadIdx.x;
  if (t < N) { cursor[t] = 0; return; }
  t -= N;
  const int wjobs = 6 * 9216;
  if (t < wjobs) {
    int mat = t / 9216, idx = t - mat * 9216;
    int l = mat >> 1, which = mat & 1;
    int k = idx / 96, n = idx - k * 96;
    const float* src = (which ? W2 : W1) + (size_t)l * 9216;
    wt[(size_t)mat * 9216 + n * 96 + k] = f2bf(src[k * 96 + n]);
  } else {
    int u = t - wjobs;
    if (u < total8) {
      int i = u / 12, c8 = u - i * 12;
      float4 a = x4[2 * u], b = x4[2 * u + 1];
      u16x8 o;
      o[0] = f2bf(a.x); o[1] = f2bf(a.y); o[2] = f2bf(a.z); o[3] = f2bf(a.w);
      o[4] = f2bf(b.x); o[5] = f2bf(b.y); o[6] = f2bf(b.z); o[7] = f2bf(b.w);
      unsigned short* dst = (c8 < 6) ? (hlo + (size_t)i * 48 + c8 * 8)
                                     : (hhi + (size_t)i * 48 + (c8 - 6) * 8);
      *reinterpret_cast<u16x8*>(dst) = o;
    }
  }
}

// XCD-partitioned bucketed fill (see R11).
__global__ __launch_bounds__(TPB) void fill_kernel(const int* __restrict__ src,
                                                   const int* __restrict__ dst,
                                                   int* __restrict__ cursor,
                                                   unsigned short* __restrict__ csr16,
                                                   int N, int E) {
  const int g = blockIdx.x & 7;
  const int bid = blockIdx.x >> 3;
  const int nblk = gridDim.x >> 3;
  const int chunk = (N + 7) >> 3;
  const int lo = g * chunk;
  const unsigned span = (unsigned)((N - lo < chunk) ? (N - lo) : chunk);
  const int gsz = nblk * TPB;
  for (int t = bid * TPB + threadIdx.x; 4 * t < E; t += gsz) {
    int base = 4 * t;
    if (base + 4 <= E) {
      int4 d4 = *reinterpret_cast<const int4*>(dst + base);
      int4 s4 = *reinterpret_cast<const int4*>(src + base);
      if ((unsigned)(d4.x - lo) < span) {
        int slot = atomicAdd(&cursor[d4.x], 1);
        csr16[(size_t)d4.x * BS + slot] = (unsigned short)s4.x;
      }
      if ((unsigned)(d4.y - lo) < span) {
        int slot = atomicAdd(&cursor[d4.y], 1);
        csr16[(size_t)d4.y * BS + slot] = (unsigned short)s4.y;
      }
      if ((unsigned)(d4.z - lo) < span) {
        int slot = atomicAdd(&cursor[d4.z], 1);
        csr16[(size_t)d4.z * BS + slot] = (unsigned short)s4.z;
      }
      if ((unsigned)(d4.w - lo) < span) {
        int slot = atomicAdd(&cursor[d4.w], 1);
        csr16[(size_t)d4.w * BS + slot] = (unsigned short)s4.w;
      }
    } else {
      for (int e = base; e < E; e++) {
        int d = dst[e];
        if ((unsigned)(d - lo) < span) {
          int slot = atomicAdd(&cursor[d], 1);
          csr16[(size_t)d * BS + slot] = (unsigned short)src[e];
        }
      }
    }
  }
}

// One feature-half pass: agg[i][HALF half] from h_half (row stride 48 bf16 =
// 6 u16x8 chunks). 6 threads/node. Gather working set = 4.8MB (L2-resident).
__global__ __launch_bounds__(TPB) void aggb_kernel(const u16x8* __restrict__ hin6,
                                                   u16x8* __restrict__ aggbuf12,
                                                   const int* __restrict__ deg,
                                                   const unsigned short* __restrict__ csr16,
                                                   int n, int half) {
  int t = blockIdx.x * TPB + threadIdx.x;
  if (t >= n * 6) return;
  int i = t / 6;
  int f = t - i * 6;
  const unsigned short* row = csr16 + (size_t)i * BS;
  u16x8 self = hin6[(size_t)i * 6 + f];
  float acc[8];
#pragma unroll
  for (int k = 0; k < 8; k++) acc[k] = bf2f(self[k]);
  int e = deg[i];
  int j = 0;
  for (; j + 8 <= e; j += 8) {
    u16x8 idx = *reinterpret_cast<const u16x8*>(row + j);
    u16x8 v0 = hin6[(size_t)idx[0] * 6 + f];
    u16x8 v1 = hin6[(size_t)idx[1] * 6 + f];
    u16x8 v2 = hin6[(size_t)idx[2] * 6 + f];
    u16x8 v3 = hin6[(size_t)idx[3] * 6 + f];
    u16x8 v4 = hin6[(size_t)idx[4] * 6 + f];
    u16x8 v5 = hin6[(size_t)idx[5] * 6 + f];
    u16x8 v6 = hin6[(size_t)idx[6] * 6 + f];
    u16x8 v7 = hin6[(size_t)idx[7] * 6 + f];
#pragma unroll
    for (int k = 0; k < 8; k++)
      acc[k] += ((bf2f(v0[k]) + bf2f(v1[k])) + (bf2f(v2[k]) + bf2f(v3[k]))) +
                ((bf2f(v4[k]) + bf2f(v5[k])) + (bf2f(v6[k]) + bf2f(v7[k])));
  }
  if (j + 4 <= e) {
    int i0 = row[j], i1 = row[j + 1], i2 = row[j + 2], i3 = row[j + 3];
    u16x8 v0 = hin6[(size_t)i0 * 6 + f];
    u16x8 v1 = hin6[(size_t)i1 * 6 + f];
    u16x8 v2 = hin6[(size_t)i2 * 6 + f];
    u16x8 v3 = hin6[(size_t)i3 * 6 + f];
#pragma unroll
    for (int k = 0; k < 8; k++)
      acc[k] += (bf2f(v0[k]) + bf2f(v1[k])) + (bf2f(v2[k]) + bf2f(v3[k]));
    j += 4;
  }
  for (; j < e; j++) {
    u16x8 v = hin6[(size_t)row[j] * 6 + f];
#pragma unroll
    for (int k = 0; k < 8; k++) acc[k] += bf2f(v[k]);
  }
  u16x8 o;
#pragma unroll
  for (int k = 0; k < 8; k++) o[k] = f2bf(acc[k]);
  aggbuf12[(size_t)i * 12 + 6 * half + f] = o;
}

// h = relu( relu(agg@W1+B1) @ W2 + B2 ), h written split (hlo/hhi);
// LAST computes out = h@Wc + Bc instead. Block: 64 rows, 4 waves.
template <bool LAST>
__global__ __launch_bounds__(TPB) void mlp_mfma_kernel(
    const u16x8* __restrict__ in8, const unsigned short* __restrict__ wt1,
    const unsigned short* __restrict__ wt2, const float* __restrict__ B1,
    const float* __restrict__ B2, unsigned short* __restrict__ hlo,
    unsigned short* __restrict__ hhi,
    const float* __restrict__ Wc, const float* __restrict__ Bc,
    float* __restrict__ outf, int nrows) {
  __shared__ unsigned short A_lds[64 * LDA];   // A tile, later Z tile
  __shared__ unsigned short W1_lds[96 * LDA];
  __shared__ unsigned short W2_lds[96 * LDA];
  const int tid = threadIdx.x;
  const int row0 = blockIdx.x * 64;

  // stage A (already bf16), rows [row0, row0+64)
  for (int t = tid; t < 64 * 12; t += TPB) {
    int r = t / 12, c8 = t - r * 12;
    int gr = row0 + r;
    u16x8 v = {};
    if (gr < nrows) v = in8[(size_t)gr * 12 + c8];
    *reinterpret_cast<u16x8*>(&A_lds[r * LDA + 8 * c8]) = v;
  }
  // stage Wt1, Wt2 (bf16, 16B chunks)
  for (int t = tid; t < 2 * 1152; t += TPB) {
    int which = t / 1152, idx = t - which * 1152;
    int n = idx / 12, c8 = idx - n * 12;
    const unsigned short* src = (which ? wt2 : wt1) + n * 96 + 8 * c8;
    bfrag8 v = *reinterpret_cast<const bfrag8*>(src);
    unsigned short* dp = (which ? W2_lds : W1_lds) + n * LDA + 8 * c8;
    *reinterpret_cast<bfrag8*>(dp) = v;
  }
  __syncthreads();

  const int lane = tid & 63;
  const int w = tid >> 6;     // wave id: rows [16w, 16w+16)
  const int nl = lane & 15;   // frag row (A) / col (B,D)
  const int q = lane >> 4;    // k-quarter
  const int arow = 16 * w + nl;

  bfrag8 afrag[3];
#pragma unroll
  for (int s = 0; s < 3; s++)
    afrag[s] = *reinterpret_cast<const bfrag8*>(&A_lds[arow * LDA + 32 * s + 8 * q]);

  // GEMM1 -> relu -> Z (bf16) into this wave's own A stripe (no barrier needed)
#pragma unroll
  for (int cb = 0; cb < 6; cb++) {
    f32x4 acc = {0.f, 0.f, 0.f, 0.f};
#pragma unroll
    for (int s = 0; s < 3; s++) {
      bfrag8 bfr = *reinterpret_cast<const bfrag8*>(
          &W1_lds[(16 * cb + nl) * LDA + 32 * s + 8 * q]);
      acc = __builtin_amdgcn_mfma_f32_16x16x32_bf16(afrag[s], bfr, acc, 0, 0, 0);
    }
    float b = B1[16 * cb + nl];
#pragma unroll
    for (int i = 0; i < 4; i++) {
      int m = 16 * w + 4 * q + i;
      A_lds[m * LDA + 16 * cb + nl] = f2bf(fmaxf(acc[i] + b, 0.f));
    }
  }

  bfrag8 zfrag[3];
#pragma unroll
  for (int s = 0; s < 3; s++)
    zfrag[s] = *reinterpret_cast<const bfrag8*>(&A_lds[arow * LDA + 32 * s + 8 * q]);

  float oacc[40];  // LAST only: per-lane partial out[i][c], static-indexed
#pragma unroll
  for (int t2 = 0; t2 < 40; t2++) oacc[t2] = 0.f;

#pragma unroll
  for (int cb = 0; cb < 6; cb++) {
    f32x4 acc = {0.f, 0.f, 0.f, 0.f};
#pragma unroll
    for (int s = 0; s < 3; s++) {
      bfrag8 bfr = *reinterpret_cast<const bfrag8*>(
          &W2_lds[(16 * cb + nl) * LDA + 32 * s + 8 * q]);
      acc = __builtin_amdgcn_mfma_f32_16x16x32_bf16(zfrag[s], bfr, acc, 0, 0, 0);
    }
    float b = B2[16 * cb + nl];
#pragma unroll
    for (int i = 0; i < 4; i++) {
      float hv = fmaxf(acc[i] + b, 0.f);
      if (!LAST) {
        int m = 16 * w + 4 * q + i;
        int gr = row0 + m;
        if (gr < nrows) {
          int col = 16 * cb + nl;   // cb is unroll-constant: branch is static
          if (cb < 3) hlo[(size_t)gr * 48 + col] = f2bf(hv);
          else        hhi[(size_t)gr * 48 + (col - 48)] = f2bf(hv);
        }
      } else {
#pragma unroll
        for (int c = 0; c < 10; c++)
          oacc[i * 10 + c] += hv * Wc[(16 * cb + nl) * 10 + c];
      }
    }
  }

  if (LAST) {
    // reduce over the 16 nl-lanes within each q-group
#pragma unroll
    for (int m = 1; m < 16; m <<= 1) {
#pragma unroll
      for (int t2 = 0; t2 < 40; t2++) oacc[t2] += __shfl_xor(oacc[t2], m, 64);
    }
#pragma unroll
    for (int i = 0; i < 4; i++) {
      int gr = row0 + 16 * w + 4 * q + i;
      if (gr < nrows && nl < 10) {
        float v = 0.f;
#pragma unroll
        for (int c = 0; c < 10; c++)
          if (nl == c) v = oacc[i * 10 + c];
        outf[(size_t)gr * 10 + nl] = v + Bc[nl];
      }
    }
  }
}

extern "C" void kernel_launch(void* const* d_in, const int* in_sizes, int n_in,
                              void* d_out, int out_size, void* d_ws, size_t ws_size,
                              hipStream_t stream) {
  const float* x  = (const float*)d_in[0];
  const int*   ei = (const int*)d_in[1];
  const float* W1 = (const float*)d_in[2];
  const float* B1 = (const float*)d_in[3];
  const float* W2 = (const float*)d_in[4];
  const float* B2 = (const float*)d_in[5];
  const float* Wc = (const float*)d_in[6];
  const float* Bc = (const float*)d_in[7];
  float* out = (float*)d_out;

  const int N = in_sizes[0] / 96;
  const int E = in_sizes[1] / 2;
  const int* src = ei;       // edge_index[0]
  const int* dst = ei + E;   // edge_index[1]

  unsigned short* hlo    = (unsigned short*)d_ws;        // N*48 bf16
  unsigned short* hhi    = hlo + (size_t)N * 48;         // N*48 bf16
  unsigned short* aggbuf = hhi + (size_t)N * 48;         // N*96 bf16
  int* cursor = (int*)(aggbuf + (size_t)N * 96);         // N int (deg after fill)
  unsigned short* csr16 = (unsigned short*)(cursor + N); // N*BS u16
  unsigned short* wt    = csr16 + (size_t)N * BS;        // 6*9216 u16

  const int total8 = N * 12;
  const int prep_jobs = N + 6 * 9216 + total8;
  prep_kernel<<<(prep_jobs + TPB - 1) / TPB, TPB, 0, stream>>>(
      cursor, N, W1, W2, wt, (const float4*)x, hlo, hhi, total8);

  fill_kernel<<<1024, TPB, 0, stream>>>(src, dst, cursor, csr16, N, E);

  const int aggblk = (N * 6 + TPB - 1) / TPB;
  for (int l = 0; l < 3; l++) {
    aggb_kernel<<<aggblk, TPB, 0, stream>>>(
        (const u16x8*)hlo, (u16x8*)aggbuf, cursor, csr16, N, 0);
    aggb_kernel<<<aggblk, TPB, 0, stream>>>(
        (const u16x8*)hhi, (u16x8*)aggbuf, cursor, csr16, N, 1);
    const unsigned short* wt1 = wt + (size_t)(l * 2) * 9216;
    const unsigned short* wt2 = wt + (size_t)(l * 2 + 1) * 9216;
    const float* b1 = B1 + (size_t)l * 96;
    const float* b2 = B2 + (size_t)l * 96;
    if (l < 2)
      mlp_mfma_kernel<false><<<(N + 63) / 64, TPB, 0, stream>>>(
          (const u16x8*)aggbuf, wt1, wt2, b1, b2, hlo, hhi, Wc, Bc, out, N);
    else
      mlp_mfma_kernel<true><<<(N + 63) / 64, TPB, 0, stream>>>(
          (const u16x8*)aggbuf, wt1, wt2, b1, b2, hlo, hhi, Wc, Bc, out, N);
  }
}

// Round 14
// 186.590 us; speedup vs baseline: 1.0831x; 1.0831x over previous
//
#include <hip/hip_runtime.h>

// StackedGIN: L=3 layers of { agg = h + scatter_sum(h[src] -> dst);
//   h = relu( relu(agg@W1+B1) @ W2 + B2 ) }, then out = h@Wc + Bc.
// N=50000, E=800000, D=96, C=10.
//
// R1: float4 gather.  R2: wave-scan slots.  R3: bf16 MFMA MLP.
// R4: h/agg bf16.  R5: prep fuse + fused classifier.  R6: no coop launch.
// R7 FAILED: agg-in-MLP capped occupancy.  R8: u16 csr.  R9: own zero.
// R10 NEUTRAL: fill was line-ping-pong bound, not latency bound.
// R11: bucketed CSR (stride 64) + XCD-partitioned fill. 236->189us.
// R12 FAILED (reverted): feature-split h broke 64B row alignment (1.5-line
//     rows -> gather overfetch) + doubled requests + 3 extra gaps. 202us.
// R13: R11 structure + __builtin_nontemporal_store on aggbuf/h/out streams
//     (streaming writes were write-allocating in L2, evicting gather-source
//     h lines; h lines are only L2-useful on their writer XCD anyway).
// ws layout: hbuf(N*96 bf16) | aggbuf(N*96 bf16) | cursor(N) |
//            csr16(N*64 u16) | wt(6*9216 u16)

#define TPB 256
#define LDA 104  // bf16 elems per LDS row: 96 + 8 pad
#define BS 64    // csr bucket stride per node

typedef __attribute__((ext_vector_type(8))) short bfrag8;
typedef __attribute__((ext_vector_type(8))) unsigned short u16x8;
typedef __attribute__((ext_vector_type(4))) float f32x4;

__device__ inline unsigned short f2bf(float x) {  // RNE f32 -> bf16 bits
  unsigned int u = __float_as_uint(x);
  unsigned int r = u + 0x7FFFu + ((u >> 16) & 1u);
  return (unsigned short)(r >> 16);
}
__device__ inline float bf2f(unsigned short u) {
  return __uint_as_float(((unsigned int)u) << 16);
}

// jobs: [0,N) zero cursor; then weight transpose->bf16; then x->bf16.
__global__ __launch_bounds__(TPB) void prep_kernel(
    int* __restrict__ cursor, int N,
    const float* __restrict__ W1, const float* __restrict__ W2,
    unsigned short* __restrict__ wt,
    const float4* __restrict__ x4, u16x8* __restrict__ h8, int total8) {
  int t = blockIdx.x * TPB + threadIdx.x;
  if (t < N) { cursor[t] = 0; return; }
  t -= N;
  const int wjobs = 6 * 9216;
  if (t < wjobs) {
    int mat = t / 9216, idx = t - mat * 9216;
    int l = mat >> 1, which = mat & 1;
    int k = idx / 96, n = idx - k * 96;
    const float* src = (which ? W2 : W1) + (size_t)l * 9216;
    wt[(size_t)mat * 9216 + n * 96 + k] = f2bf(src[k * 96 + n]);
  } else {
    int u = t - wjobs;
    if (u < total8) {
      float4 a = x4[2 * u], b = x4[2 * u + 1];
      u16x8 o;
      o[0] = f2bf(a.x); o[1] = f2bf(a.y); o[2] = f2bf(a.z); o[3] = f2bf(a.w);
      o[4] = f2bf(b.x); o[5] = f2bf(b.y); o[6] = f2bf(b.z); o[7] = f2bf(b.w);
      h8[u] = o;
    }
  }
}

// XCD-partitioned bucketed fill: group g = blockIdx&7 owns dst range
// [g*chunk,(g+1)*chunk); every group streams all edges (L3-served), handles
// only its own -> cursor/csr lines are single-XCD, no line migration.
__global__ __launch_bounds__(TPB) void fill_kernel(const int* __restrict__ src,
                                                   const int* __restrict__ dst,
                                                   int* __restrict__ cursor,
                                                   unsigned short* __restrict__ csr16,
                                                   int N, int E) {
  const int g = blockIdx.x & 7;
  const int bid = blockIdx.x >> 3;
  const int nblk = gridDim.x >> 3;
  const int chunk = (N + 7) >> 3;
  const int lo = g * chunk;
  const unsigned span = (unsigned)((N - lo < chunk) ? (N - lo) : chunk);
  const int gsz = nblk * TPB;
  for (int t = bid * TPB + threadIdx.x; 4 * t < E; t += gsz) {
    int base = 4 * t;
    if (base + 4 <= E) {
      int4 d4 = *reinterpret_cast<const int4*>(dst + base);
      int4 s4 = *reinterpret_cast<const int4*>(src + base);
      if ((unsigned)(d4.x - lo) < span) {
        int slot = atomicAdd(&cursor[d4.x], 1);
        csr16[(size_t)d4.x * BS + slot] = (unsigned short)s4.x;
      }
      if ((unsigned)(d4.y - lo) < span) {
        int slot = atomicAdd(&cursor[d4.y], 1);
        csr16[(size_t)d4.y * BS + slot] = (unsigned short)s4.y;
      }
      if ((unsigned)(d4.z - lo) < span) {
        int slot = atomicAdd(&cursor[d4.z], 1);
        csr16[(size_t)d4.z * BS + slot] = (unsigned short)s4.z;
      }
      if ((unsigned)(d4.w - lo) < span) {
        int slot = atomicAdd(&cursor[d4.w], 1);
        csr16[(size_t)d4.w * BS + slot] = (unsigned short)s4.w;
      }
    } else {
      for (int e = base; e < E; e++) {
        int d = dst[e];
        if ((unsigned)(d - lo) < span) {
          int slot = atomicAdd(&cursor[d], 1);
          csr16[(size_t)d * BS + slot] = (unsigned short)src[e];
        }
      }
    }
  }
}

// agg[i][c8] = h[i][c8] + sum_{j<deg[i]} h[csr[i*BS+j]][c8]; bf16 in/out,
// f32 accumulate. 12 threads/node; 8 neighbor indices loaded per u16x8.
// Output store is non-temporal (read once, streaming, by mlp).
__global__ __launch_bounds__(TPB) void aggb_kernel(const u16x8* __restrict__ hin8,
                                                   u16x8* __restrict__ hout8,
                                                   const int* __restrict__ deg,
                                                   const unsigned short* __restrict__ csr16,
                                                   int n) {
  int t = blockIdx.x * TPB + threadIdx.x;
  if (t >= n * 12) return;
  int i = t / 12;
  int f = t - i * 12;
  const unsigned short* row = csr16 + (size_t)i * BS;
  u16x8 self = hin8[t];
  float acc[8];
#pragma unroll
  for (int k = 0; k < 8; k++) acc[k] = bf2f(self[k]);
  int e = deg[i];
  int j = 0;
  for (; j + 8 <= e; j += 8) {
    u16x8 idx = *reinterpret_cast<const u16x8*>(row + j);
    u16x8 v0 = hin8[(size_t)idx[0] * 12 + f];
    u16x8 v1 = hin8[(size_t)idx[1] * 12 + f];
    u16x8 v2 = hin8[(size_t)idx[2] * 12 + f];
    u16x8 v3 = hin8[(size_t)idx[3] * 12 + f];
    u16x8 v4 = hin8[(size_t)idx[4] * 12 + f];
    u16x8 v5 = hin8[(size_t)idx[5] * 12 + f];
    u16x8 v6 = hin8[(size_t)idx[6] * 12 + f];
    u16x8 v7 = hin8[(size_t)idx[7] * 12 + f];
#pragma unroll
    for (int k = 0; k < 8; k++)
      acc[k] += ((bf2f(v0[k]) + bf2f(v1[k])) + (bf2f(v2[k]) + bf2f(v3[k]))) +
                ((bf2f(v4[k]) + bf2f(v5[k])) + (bf2f(v6[k]) + bf2f(v7[k])));
  }
  if (j + 4 <= e) {
    int i0 = row[j], i1 = row[j + 1], i2 = row[j + 2], i3 = row[j + 3];
    u16x8 v0 = hin8[(size_t)i0 * 12 + f];
    u16x8 v1 = hin8[(size_t)i1 * 12 + f];
    u16x8 v2 = hin8[(size_t)i2 * 12 + f];
    u16x8 v3 = hin8[(size_t)i3 * 12 + f];
#pragma unroll
    for (int k = 0; k < 8; k++)
      acc[k] += (bf2f(v0[k]) + bf2f(v1[k])) + (bf2f(v2[k]) + bf2f(v3[k]));
    j += 4;
  }
  for (; j < e; j++) {
    u16x8 v = hin8[(size_t)row[j] * 12 + f];
#pragma unroll
    for (int k = 0; k < 8; k++) acc[k] += bf2f(v[k]);
  }
  u16x8 o;
#pragma unroll
  for (int k = 0; k < 8; k++) o[k] = f2bf(acc[k]);
  __builtin_nontemporal_store(o, &hout8[t]);
}

// h = relu( relu(agg@W1+B1) @ W2 + B2 ); LAST also computes out = h@Wc + Bc
// (h never stored for the last layer). Block: 64 rows, 4 waves x 16-row stripe.
// h/out stores non-temporal (h is only L2-useful on its writer XCD).
template <bool LAST>
__global__ __launch_bounds__(TPB) void mlp_mfma_kernel(
    const u16x8* __restrict__ in8, const unsigned short* __restrict__ wt1,
    const unsigned short* __restrict__ wt2, const float* __restrict__ B1,
    const float* __restrict__ B2, unsigned short* __restrict__ out,
    const float* __restrict__ Wc, const float* __restrict__ Bc,
    float* __restrict__ outf, int nrows) {
  __shared__ unsigned short A_lds[64 * LDA];   // A tile, later Z tile
  __shared__ unsigned short W1_lds[96 * LDA];
  __shared__ unsigned short W2_lds[96 * LDA];
  const int tid = threadIdx.x;
  const int row0 = blockIdx.x * 64;

  // stage A (already bf16), rows [row0, row0+64)
  for (int t = tid; t < 64 * 12; t += TPB) {
    int r = t / 12, c8 = t - r * 12;
    int gr = row0 + r;
    u16x8 v = {};
    if (gr < nrows) v = in8[(size_t)gr * 12 + c8];
    *reinterpret_cast<u16x8*>(&A_lds[r * LDA + 8 * c8]) = v;
  }
  // stage Wt1, Wt2 (bf16, 16B chunks)
  for (int t = tid; t < 2 * 1152; t += TPB) {
    int which = t / 1152, idx = t - which * 1152;
    int n = idx / 12, c8 = idx - n * 12;
    const unsigned short* src = (which ? wt2 : wt1) + n * 96 + 8 * c8;
    bfrag8 v = *reinterpret_cast<const bfrag8*>(src);
    unsigned short* dp = (which ? W2_lds : W1_lds) + n * LDA + 8 * c8;
    *reinterpret_cast<bfrag8*>(dp) = v;
  }
  __syncthreads();

  const int lane = tid & 63;
  const int w = tid >> 6;     // wave id: rows [16w, 16w+16)
  const int nl = lane & 15;   // frag row (A) / col (B,D)
  const int q = lane >> 4;    // k-quarter
  const int arow = 16 * w + nl;

  bfrag8 afrag[3];
#pragma unroll
  for (int s = 0; s < 3; s++)
    afrag[s] = *reinterpret_cast<const bfrag8*>(&A_lds[arow * LDA + 32 * s + 8 * q]);

  // GEMM1 -> relu -> Z (bf16) into this wave's own A stripe (no barrier needed)
#pragma unroll
  for (int cb = 0; cb < 6; cb++) {
    f32x4 acc = {0.f, 0.f, 0.f, 0.f};
#pragma unroll
    for (int s = 0; s < 3; s++) {
      bfrag8 bfr = *reinterpret_cast<const bfrag8*>(
          &W1_lds[(16 * cb + nl) * LDA + 32 * s + 8 * q]);
      acc = __builtin_amdgcn_mfma_f32_16x16x32_bf16(afrag[s], bfr, acc, 0, 0, 0);
    }
    float b = B1[16 * cb + nl];
#pragma unroll
    for (int i = 0; i < 4; i++) {
      int m = 16 * w + 4 * q + i;
      A_lds[m * LDA + 16 * cb + nl] = f2bf(fmaxf(acc[i] + b, 0.f));
    }
  }

  bfrag8 zfrag[3];
#pragma unroll
  for (int s = 0; s < 3; s++)
    zfrag[s] = *reinterpret_cast<const bfrag8*>(&A_lds[arow * LDA + 32 * s + 8 * q]);

  float oacc[40];  // LAST only: per-lane partial out[i][c], static-indexed
#pragma unroll
  for (int t2 = 0; t2 < 40; t2++) oacc[t2] = 0.f;

#pragma unroll
  for (int cb = 0; cb < 6; cb++) {
    f32x4 acc = {0.f, 0.f, 0.f, 0.f};
#pragma unroll
    for (int s = 0; s < 3; s++) {
      bfrag8 bfr = *reinterpret_cast<const bfrag8*>(
          &W2_lds[(16 * cb + nl) * LDA + 32 * s + 8 * q]);
      acc = __builtin_amdgcn_mfma_f32_16x16x32_bf16(zfrag[s], bfr, acc, 0, 0, 0);
    }
    float b = B2[16 * cb + nl];
#pragma unroll
    for (int i = 0; i < 4; i++) {
      float hv = fmaxf(acc[i] + b, 0.f);
      if (!LAST) {
        int m = 16 * w + 4 * q + i;
        int gr = row0 + m;
        if (gr < nrows)
          __builtin_nontemporal_store(f2bf(hv), &out[(size_t)gr * 96 + 16 * cb + nl]);
      } else {
#pragma unroll
        for (int c = 0; c < 10; c++)
          oacc[i * 10 + c] += hv * Wc[(16 * cb + nl) * 10 + c];
      }
    }
  }

  if (LAST) {
    // reduce over the 16 nl-lanes within each q-group
#pragma unroll
    for (int m = 1; m < 16; m <<= 1) {
#pragma unroll
      for (int t2 = 0; t2 < 40; t2++) oacc[t2] += __shfl_xor(oacc[t2], m, 64);
    }
#pragma unroll
    for (int i = 0; i < 4; i++) {
      int gr = row0 + 16 * w + 4 * q + i;
      if (gr < nrows && nl < 10) {
        float v = 0.f;
#pragma unroll
        for (int c = 0; c < 10; c++)
          if (nl == c) v = oacc[i * 10 + c];
        __builtin_nontemporal_store(v + Bc[nl], &outf[(size_t)gr * 10 + nl]);
      }
    }
  }
}

extern "C" void kernel_launch(void* const* d_in, const int* in_sizes, int n_in,
                              void* d_out, int out_size, void* d_ws, size_t ws_size,
                              hipStream_t stream) {
  const float* x  = (const float*)d_in[0];
  const int*   ei = (const int*)d_in[1];
  const float* W1 = (const float*)d_in[2];
  const float* B1 = (const float*)d_in[3];
  const float* W2 = (const float*)d_in[4];
  const float* B2 = (const float*)d_in[5];
  const float* Wc = (const float*)d_in[6];
  const float* Bc = (const float*)d_in[7];
  float* out = (float*)d_out;

  const int N = in_sizes[0] / 96;
  const int E = in_sizes[1] / 2;
  const int* src = ei;       // edge_index[0]
  const int* dst = ei + E;   // edge_index[1]

  unsigned short* hbuf   = (unsigned short*)d_ws;        // N*96 bf16
  unsigned short* aggbuf = hbuf + (size_t)N * 96;        // N*96 bf16
  int* cursor = (int*)(aggbuf + (size_t)N * 96);         // N int (deg after fill)
  unsigned short* csr16 = (unsigned short*)(cursor + N); // N*BS u16
  unsigned short* wt    = csr16 + (size_t)N * BS;        // 6*9216 u16

  const int total8 = N * 12;
  const int prep_jobs = N + 6 * 9216 + total8;
  prep_kernel<<<(prep_jobs + TPB - 1) / TPB, TPB, 0, stream>>>(
      cursor, N, W1, W2, wt, (const float4*)x, (u16x8*)hbuf, total8);

  fill_kernel<<<1024, TPB, 0, stream>>>(src, dst, cursor, csr16, N, E);

  for (int l = 0; l < 3; l++) {
    aggb_kernel<<<((N * 12) + TPB - 1) / TPB, TPB, 0, stream>>>(
        (const u16x8*)hbuf, (u16x8*)aggbuf, cursor, csr16, N);
    const unsigned short* wt1 = wt + (size_t)(l * 2) * 9216;
    const unsigned short* wt2 = wt + (size_t)(l * 2 + 1) * 9216;
    const float* b1 = B1 + (size_t)l * 96;
    const float* b2 = B2 + (size_t)l * 96;
    if (l < 2)
      mlp_mfma_kernel<false><<<(N + 63) / 64, TPB, 0, stream>>>(
          (const u16x8*)aggbuf, wt1, wt2, b1, b2, hbuf, Wc, Bc, out, N);
    else
      mlp_mfma_kernel<true><<<(N + 63) / 64, TPB, 0, stream>>>(
          (const u16x8*)aggbuf, wt1, wt2, b1, b2, hbuf, Wc, Bc, out, N);
  }
}

// Round 16
// 181.161 us; speedup vs baseline: 1.1156x; 1.0300x over previous
//
#include <hip/hip_runtime.h>

// StackedGIN: L=3 layers of { agg = h + scatter_sum(h[src] -> dst);
//   h = relu( relu(agg@W1+B1) @ W2 + B2 ) }, then out = h@Wc + Bc.
// N=50000, E=800000, D=96, C=10.
//
// R1: float4 gather.  R2: wave-scan slots.  R3: bf16 MFMA MLP.
// R4: h/agg bf16.  R5: prep fuse + fused classifier.  R6: no coop launch.
// R7 FAILED: agg-in-MLP capped occupancy.  R8: u16 csr.  R9: own zero.
// R10 NEUTRAL: fill was line-ping-pong bound.  R11: bucketed CSR +
//     XCD-partitioned fill (236->189).  R12 FAILED: feature-split h broke
//     line alignment.  R13: nt stores on streaming writes (189->186.6).
// R14/R15: (a) fill: nt LOADS on edge streams (they thrash the owner XCD's
//     L2, evicting csr lines -> 4.4x write-back amplification) + skip src
//     int4 when no dst matches. (b) mlp: drop W1/W2 LDS staging, read
//     B-fragments straight from global wt (L2 broadcast); LDS 53->13.3KB.
//     (R15 = R14 with clang ext_vector i32x4 for nontemporal loads —
//     __builtin_nontemporal_load rejects HIP_vector_type int4.)
// ws layout: hbuf(N*96 bf16) | aggbuf(N*96 bf16) | cursor(N) |
//            csr16(N*64 u16) | wt(6*9216 u16)

#define TPB 256
#define LDA 104  // bf16 elems per LDS row: 96 + 8 pad
#define BS 64    // csr bucket stride per node

typedef __attribute__((ext_vector_type(8))) short bfrag8;
typedef __attribute__((ext_vector_type(8))) unsigned short u16x8;
typedef __attribute__((ext_vector_type(4))) float f32x4;
typedef __attribute__((ext_vector_type(4))) int i32x4;

__device__ inline unsigned short f2bf(float x) {  // RNE f32 -> bf16 bits
  unsigned int u = __float_as_uint(x);
  unsigned int r = u + 0x7FFFu + ((u >> 16) & 1u);
  return (unsigned short)(r >> 16);
}
__device__ inline float bf2f(unsigned short u) {
  return __uint_as_float(((unsigned int)u) << 16);
}

// jobs: [0,N) zero cursor; then weight transpose->bf16; then x->bf16.
__global__ __launch_bounds__(TPB) void prep_kernel(
    int* __restrict__ cursor, int N,
    const float* __restrict__ W1, const float* __restrict__ W2,
    unsigned short* __restrict__ wt,
    const float4* __restrict__ x4, u16x8* __restrict__ h8, int total8) {
  int t = blockIdx.x * TPB + threadIdx.x;
  if (t < N) { cursor[t] = 0; return; }
  t -= N;
  const int wjobs = 6 * 9216;
  if (t < wjobs) {
    int mat = t / 9216, idx = t - mat * 9216;
    int l = mat >> 1, which = mat & 1;
    int k = idx / 96, n = idx - k * 96;
    const float* src = (which ? W2 : W1) + (size_t)l * 9216;
    wt[(size_t)mat * 9216 + n * 96 + k] = f2bf(src[k * 96 + n]);
  } else {
    int u = t - wjobs;
    if (u < total8) {
      float4 a = x4[2 * u], b = x4[2 * u + 1];
      u16x8 o;
      o[0] = f2bf(a.x); o[1] = f2bf(a.y); o[2] = f2bf(a.z); o[3] = f2bf(a.w);
      o[4] = f2bf(b.x); o[5] = f2bf(b.y); o[6] = f2bf(b.z); o[7] = f2bf(b.w);
      h8[u] = o;
    }
  }
}

// XCD-partitioned bucketed fill: group g = blockIdx&7 owns dst range.
// Edge streams are non-temporal (don't evict the group's resident csr
// lines); src vector loaded only if some lane of it matches the range.
__global__ __launch_bounds__(TPB) void fill_kernel(const int* __restrict__ src,
                                                   const int* __restrict__ dst,
                                                   int* __restrict__ cursor,
                                                   unsigned short* __restrict__ csr16,
                                                   int N, int E) {
  const int g = blockIdx.x & 7;
  const int bid = blockIdx.x >> 3;
  const int nblk = gridDim.x >> 3;
  const int chunk = (N + 7) >> 3;
  const int lo = g * chunk;
  const unsigned span = (unsigned)((N - lo < chunk) ? (N - lo) : chunk);
  const int gsz = nblk * TPB;
  for (int t = bid * TPB + threadIdx.x; 4 * t < E; t += gsz) {
    int base = 4 * t;
    if (base + 4 <= E) {
      i32x4 d4 = __builtin_nontemporal_load(reinterpret_cast<const i32x4*>(dst + base));
      bool m0 = (unsigned)(d4[0] - lo) < span;
      bool m1 = (unsigned)(d4[1] - lo) < span;
      bool m2 = (unsigned)(d4[2] - lo) < span;
      bool m3 = (unsigned)(d4[3] - lo) < span;
      if (m0 | m1 | m2 | m3) {
        i32x4 s4 = __builtin_nontemporal_load(reinterpret_cast<const i32x4*>(src + base));
        if (m0) {
          int slot = atomicAdd(&cursor[d4[0]], 1);
          csr16[(size_t)d4[0] * BS + slot] = (unsigned short)s4[0];
        }
        if (m1) {
          int slot = atomicAdd(&cursor[d4[1]], 1);
          csr16[(size_t)d4[1] * BS + slot] = (unsigned short)s4[1];
        }
        if (m2) {
          int slot = atomicAdd(&cursor[d4[2]], 1);
          csr16[(size_t)d4[2] * BS + slot] = (unsigned short)s4[2];
        }
        if (m3) {
          int slot = atomicAdd(&cursor[d4[3]], 1);
          csr16[(size_t)d4[3] * BS + slot] = (unsigned short)s4[3];
        }
      }
    } else {
      for (int e = base; e < E; e++) {
        int d = dst[e];
        if ((unsigned)(d - lo) < span) {
          int slot = atomicAdd(&cursor[d], 1);
          csr16[(size_t)d * BS + slot] = (unsigned short)src[e];
        }
      }
    }
  }
}

// agg[i][c8] = h[i][c8] + sum_{j<deg[i]} h[csr[i*BS+j]][c8]; bf16 in/out,
// f32 accumulate. 12 threads/node; 8 neighbor indices loaded per u16x8.
__global__ __launch_bounds__(TPB) void aggb_kernel(const u16x8* __restrict__ hin8,
                                                   u16x8* __restrict__ hout8,
                                                   const int* __restrict__ deg,
                                                   const unsigned short* __restrict__ csr16,
                                                   int n) {
  int t = blockIdx.x * TPB + threadIdx.x;
  if (t >= n * 12) return;
  int i = t / 12;
  int f = t - i * 12;
  const unsigned short* row = csr16 + (size_t)i * BS;
  u16x8 self = hin8[t];
  float acc[8];
#pragma unroll
  for (int k = 0; k < 8; k++) acc[k] = bf2f(self[k]);
  int e = deg[i];
  int j = 0;
  for (; j + 8 <= e; j += 8) {
    u16x8 idx = *reinterpret_cast<const u16x8*>(row + j);
    u16x8 v0 = hin8[(size_t)idx[0] * 12 + f];
    u16x8 v1 = hin8[(size_t)idx[1] * 12 + f];
    u16x8 v2 = hin8[(size_t)idx[2] * 12 + f];
    u16x8 v3 = hin8[(size_t)idx[3] * 12 + f];
    u16x8 v4 = hin8[(size_t)idx[4] * 12 + f];
    u16x8 v5 = hin8[(size_t)idx[5] * 12 + f];
    u16x8 v6 = hin8[(size_t)idx[6] * 12 + f];
    u16x8 v7 = hin8[(size_t)idx[7] * 12 + f];
#pragma unroll
    for (int k = 0; k < 8; k++)
      acc[k] += ((bf2f(v0[k]) + bf2f(v1[k])) + (bf2f(v2[k]) + bf2f(v3[k]))) +
                ((bf2f(v4[k]) + bf2f(v5[k])) + (bf2f(v6[k]) + bf2f(v7[k])));
  }
  if (j + 4 <= e) {
    int i0 = row[j], i1 = row[j + 1], i2 = row[j + 2], i3 = row[j + 3];
    u16x8 v0 = hin8[(size_t)i0 * 12 + f];
    u16x8 v1 = hin8[(size_t)i1 * 12 + f];
    u16x8 v2 = hin8[(size_t)i2 * 12 + f];
    u16x8 v3 = hin8[(size_t)i3 * 12 + f];
#pragma unroll
    for (int k = 0; k < 8; k++)
      acc[k] += (bf2f(v0[k]) + bf2f(v1[k])) + (bf2f(v2[k]) + bf2f(v3[k]));
    j += 4;
  }
  for (; j < e; j++) {
    u16x8 v = hin8[(size_t)row[j] * 12 + f];
#pragma unroll
    for (int k = 0; k < 8; k++) acc[k] += bf2f(v[k]);
  }
  u16x8 o;
#pragma unroll
  for (int k = 0; k < 8; k++) o[k] = f2bf(acc[k]);
  __builtin_nontemporal_store(o, &hout8[t]);
}

// h = relu( relu(agg@W1+B1) @ W2 + B2 ); LAST computes out = h@Wc + Bc.
// B-fragments read directly from global wt (L2-broadcast across blocks);
// LDS holds only the A/Z tile -> 13.3KB, 8 blocks/CU.
template <bool LAST>
__global__ __launch_bounds__(TPB) void mlp_mfma_kernel(
    const u16x8* __restrict__ in8, const unsigned short* __restrict__ wt1,
    const unsigned short* __restrict__ wt2, const float* __restrict__ B1,
    const float* __restrict__ B2, unsigned short* __restrict__ out,
    const float* __restrict__ Wc, const float* __restrict__ Bc,
    float* __restrict__ outf, int nrows) {
  __shared__ unsigned short A_lds[64 * LDA];   // A tile, later Z tile
  const int tid = threadIdx.x;
  const int row0 = blockIdx.x * 64;

  // stage A (already bf16), rows [row0, row0+64)
  for (int t = tid; t < 64 * 12; t += TPB) {
    int r = t / 12, c8 = t - r * 12;
    int gr = row0 + r;
    u16x8 v = {};
    if (gr < nrows) v = in8[(size_t)gr * 12 + c8];
    *reinterpret_cast<u16x8*>(&A_lds[r * LDA + 8 * c8]) = v;
  }
  __syncthreads();

  const int lane = tid & 63;
  const int w = tid >> 6;     // wave id: rows [16w, 16w+16)
  const int nl = lane & 15;   // frag row (A) / col (B,D)
  const int q = lane >> 4;    // k-quarter
  const int arow = 16 * w + nl;

  bfrag8 afrag[3];
#pragma unroll
  for (int s = 0; s < 3; s++)
    afrag[s] = *reinterpret_cast<const bfrag8*>(&A_lds[arow * LDA + 32 * s + 8 * q]);

  // GEMM1 -> relu -> Z (bf16) into this wave's own A stripe (no barrier needed)
#pragma unroll
  for (int cb = 0; cb < 6; cb++) {
    f32x4 acc = {0.f, 0.f, 0.f, 0.f};
#pragma unroll
    for (int s = 0; s < 3; s++) {
      bfrag8 bfr = *reinterpret_cast<const bfrag8*>(
          wt1 + (size_t)(16 * cb + nl) * 96 + 32 * s + 8 * q);
      acc = __builtin_amdgcn_mfma_f32_16x16x32_bf16(afrag[s], bfr, acc, 0, 0, 0);
    }
    float b = B1[16 * cb + nl];
#pragma unroll
    for (int i = 0; i < 4; i++) {
      int m = 16 * w + 4 * q + i;
      A_lds[m * LDA + 16 * cb + nl] = f2bf(fmaxf(acc[i] + b, 0.f));
    }
  }

  bfrag8 zfrag[3];
#pragma unroll
  for (int s = 0; s < 3; s++)
    zfrag[s] = *reinterpret_cast<const bfrag8*>(&A_lds[arow * LDA + 32 * s + 8 * q]);

  float oacc[40];  // LAST only: per-lane partial out[i][c], static-indexed
#pragma unroll
  for (int t2 = 0; t2 < 40; t2++) oacc[t2] = 0.f;

#pragma unroll
  for (int cb = 0; cb < 6; cb++) {
    f32x4 acc = {0.f, 0.f, 0.f, 0.f};
#pragma unroll
    for (int s = 0; s < 3; s++) {
      bfrag8 bfr = *reinterpret_cast<const bfrag8*>(
          wt2 + (size_t)(16 * cb + nl) * 96 + 32 * s + 8 * q);
      acc = __builtin_amdgcn_mfma_f32_16x16x32_bf16(zfrag[s], bfr, acc, 0, 0, 0);
    }
    float b = B2[16 * cb + nl];
#pragma unroll
    for (int i = 0; i < 4; i++) {
      float hv = fmaxf(acc[i] + b, 0.f);
      if (!LAST) {
        int m = 16 * w + 4 * q + i;
        int gr = row0 + m;
        if (gr < nrows)
          __builtin_nontemporal_store(f2bf(hv), &out[(size_t)gr * 96 + 16 * cb + nl]);
      } else {
#pragma unroll
        for (int c = 0; c < 10; c++)
          oacc[i * 10 + c] += hv * Wc[(16 * cb + nl) * 10 + c];
      }
    }
  }

  if (LAST) {
    // reduce over the 16 nl-lanes within each q-group
#pragma unroll
    for (int m = 1; m < 16; m <<= 1) {
#pragma unroll
      for (int t2 = 0; t2 < 40; t2++) oacc[t2] += __shfl_xor(oacc[t2], m, 64);
    }
#pragma unroll
    for (int i = 0; i < 4; i++) {
      int gr = row0 + 16 * w + 4 * q + i;
      if (gr < nrows && nl < 10) {
        float v = 0.f;
#pragma unroll
        for (int c = 0; c < 10; c++)
          if (nl == c) v = oacc[i * 10 + c];
        __builtin_nontemporal_store(v + Bc[nl], &outf[(size_t)gr * 10 + nl]);
      }
    }
  }
}

extern "C" void kernel_launch(void* const* d_in, const int* in_sizes, int n_in,
                              void* d_out, int out_size, void* d_ws, size_t ws_size,
                              hipStream_t stream) {
  const float* x  = (const float*)d_in[0];
  const int*   ei = (const int*)d_in[1];
  const float* W1 = (const float*)d_in[2];
  const float* B1 = (const float*)d_in[3];
  const float* W2 = (const float*)d_in[4];
  const float* B2 = (const float*)d_in[5];
  const float* Wc = (const float*)d_in[6];
  const float* Bc = (const float*)d_in[7];
  float* out = (float*)d_out;

  const int N = in_sizes[0] / 96;
  const int E = in_sizes[1] / 2;
  const int* src = ei;       // edge_index[0]
  const int* dst = ei + E;   // edge_index[1]

  unsigned short* hbuf   = (unsigned short*)d_ws;        // N*96 bf16
  unsigned short* aggbuf = hbuf + (size_t)N * 96;        // N*96 bf16
  int* cursor = (int*)(aggbuf + (size_t)N * 96);         // N int (deg after fill)
  unsigned short* csr16 = (unsigned short*)(cursor + N); // N*BS u16
  unsigned short* wt    = csr16 + (size_t)N * BS;        // 6*9216 u16

  const int total8 = N * 12;
  const int prep_jobs = N + 6 * 9216 + total8;
  prep_kernel<<<(prep_jobs + TPB - 1) / TPB, TPB, 0, stream>>>(
      cursor, N, W1, W2, wt, (const float4*)x, (u16x8*)hbuf, total8);

  fill_kernel<<<1024, TPB, 0, stream>>>(src, dst, cursor, csr16, N, E);

  for (int l = 0; l < 3; l++) {
    aggb_kernel<<<((N * 12) + TPB - 1) / TPB, TPB, 0, stream>>>(
        (const u16x8*)hbuf, (u16x8*)aggbuf, cursor, csr16, N);
    const unsigned short* wt1 = wt + (size_t)(l * 2) * 9216;
    const unsigned short* wt2 = wt + (size_t)(l * 2 + 1) * 9216;
    const float* b1 = B1 + (size_t)l * 96;
    const float* b2 = B2 + (size_t)l * 96;
    if (l < 2)
      mlp_mfma_kernel<false><<<(N + 63) / 64, TPB, 0, stream>>>(
          (const u16x8*)aggbuf, wt1, wt2, b1, b2, hbuf, Wc, Bc, out, N);
    else
      mlp_mfma_kernel<true><<<(N + 63) / 64, TPB, 0, stream>>>(
          (const u16x8*)aggbuf, wt1, wt2, b1, b2, hbuf, Wc, Bc, out, N);
  }
}

// Round 17
// 179.317 us; speedup vs baseline: 1.1271x; 1.0103x over previous
//
#include <hip/hip_runtime.h>

// StackedGIN: L=3 layers of { agg = h + scatter_sum(h[src] -> dst);
//   h = relu( relu(agg@W1+B1) @ W2 + B2 ) }, then out = h@Wc + Bc.
// N=50000, E=800000, D=96, C=10.
//
// R1: float4 gather.  R2: wave-scan slots.  R3: bf16 MFMA MLP.
// R4: h/agg bf16.  R5: prep fuse + fused classifier.  R6: no coop launch.
// R7 FAILED: agg-in-MLP capped occupancy.  R8: u16 csr.  R9: own zero.
// R10 NEUTRAL: fill line-ping-pong bound.  R11: bucketed CSR + XCD-
//     partitioned fill (236->189).  R12 FAILED: feature-split h.
// R13: nt stores on streaming writes (189->186.6).
// R14/R15: mlp reads W from global (L2 broadcast), LDS 53->13.3KB (181.2).
//     fill nt-LOADS were a MISTAKE: no-retain in L3 -> 8 groups re-fetch
//     edge streams from HBM (FETCH 25MB vs 12.8MB ideal).
// R16: fill: revert nt loads (L3-cacheable again); grid 2048 + 8 edges/
//     thread-iteration (2x i32x4) to hide L2 atomic latency. Fill is near
//     atomic-throughput bound (19G atomic+store pairs/s measured).
// ws layout: hbuf(N*96 bf16) | aggbuf(N*96 bf16) | cursor(N) |
//            csr16(N*64 u16) | wt(6*9216 u16)

#define TPB 256
#define LDA 104  // bf16 elems per LDS row: 96 + 8 pad
#define BS 64    // csr bucket stride per node

typedef __attribute__((ext_vector_type(8))) short bfrag8;
typedef __attribute__((ext_vector_type(8))) unsigned short u16x8;
typedef __attribute__((ext_vector_type(4))) float f32x4;
typedef __attribute__((ext_vector_type(4))) int i32x4;

__device__ inline unsigned short f2bf(float x) {  // RNE f32 -> bf16 bits
  unsigned int u = __float_as_uint(x);
  unsigned int r = u + 0x7FFFu + ((u >> 16) & 1u);
  return (unsigned short)(r >> 16);
}
__device__ inline float bf2f(unsigned short u) {
  return __uint_as_float(((unsigned int)u) << 16);
}

// jobs: [0,N) zero cursor; then weight transpose->bf16; then x->bf16.
__global__ __launch_bounds__(TPB) void prep_kernel(
    int* __restrict__ cursor, int N,
    const float* __restrict__ W1, const float* __restrict__ W2,
    unsigned short* __restrict__ wt,
    const float4* __restrict__ x4, u16x8* __restrict__ h8, int total8) {
  int t = blockIdx.x * TPB + threadIdx.x;
  if (t < N) { cursor[t] = 0; return; }
  t -= N;
  const int wjobs = 6 * 9216;
  if (t < wjobs) {
    int mat = t / 9216, idx = t - mat * 9216;
    int l = mat >> 1, which = mat & 1;
    int k = idx / 96, n = idx - k * 96;
    const float* src = (which ? W2 : W1) + (size_t)l * 9216;
    wt[(size_t)mat * 9216 + n * 96 + k] = f2bf(src[k * 96 + n]);
  } else {
    int u = t - wjobs;
    if (u < total8) {
      float4 a = x4[2 * u], b = x4[2 * u + 1];
      u16x8 o;
      o[0] = f2bf(a.x); o[1] = f2bf(a.y); o[2] = f2bf(a.z); o[3] = f2bf(a.w);
      o[4] = f2bf(b.x); o[5] = f2bf(b.y); o[6] = f2bf(b.z); o[7] = f2bf(b.w);
      h8[u] = o;
    }
  }
}

// XCD-partitioned bucketed fill: group g = blockIdx&7 owns dst range
// [g*chunk,(g+1)*chunk); every group streams all edges (L3-served after
// the first group), handles only its own -> cursor/csr single-XCD.
// 8 edges per thread-iteration; plain loads (L3-cacheable).
__global__ __launch_bounds__(TPB) void fill_kernel(const int* __restrict__ src,
                                                   const int* __restrict__ dst,
                                                   int* __restrict__ cursor,
                                                   unsigned short* __restrict__ csr16,
                                                   int N, int E) {
  const int g = blockIdx.x & 7;
  const int bid = blockIdx.x >> 3;
  const int nblk = gridDim.x >> 3;
  const int chunk = (N + 7) >> 3;
  const int lo = g * chunk;
  const unsigned span = (unsigned)((N - lo < chunk) ? (N - lo) : chunk);
  const int gsz = nblk * TPB;
  const int E8 = E >> 3;  // E = 800000, divisible by 8
  for (int t = bid * TPB + threadIdx.x; t < E8; t += gsz) {
    int base = 8 * t;
    i32x4 da = *reinterpret_cast<const i32x4*>(dst + base);
    i32x4 db = *reinterpret_cast<const i32x4*>(dst + base + 4);
    bool m0 = (unsigned)(da[0] - lo) < span;
    bool m1 = (unsigned)(da[1] - lo) < span;
    bool m2 = (unsigned)(da[2] - lo) < span;
    bool m3 = (unsigned)(da[3] - lo) < span;
    bool m4 = (unsigned)(db[0] - lo) < span;
    bool m5 = (unsigned)(db[1] - lo) < span;
    bool m6 = (unsigned)(db[2] - lo) < span;
    bool m7 = (unsigned)(db[3] - lo) < span;
    if (m0 | m1 | m2 | m3) {
      i32x4 sa = *reinterpret_cast<const i32x4*>(src + base);
      if (m0) {
        int slot = atomicAdd(&cursor[da[0]], 1);
        csr16[(size_t)da[0] * BS + slot] = (unsigned short)sa[0];
      }
      if (m1) {
        int slot = atomicAdd(&cursor[da[1]], 1);
        csr16[(size_t)da[1] * BS + slot] = (unsigned short)sa[1];
      }
      if (m2) {
        int slot = atomicAdd(&cursor[da[2]], 1);
        csr16[(size_t)da[2] * BS + slot] = (unsigned short)sa[2];
      }
      if (m3) {
        int slot = atomicAdd(&cursor[da[3]], 1);
        csr16[(size_t)da[3] * BS + slot] = (unsigned short)sa[3];
      }
    }
    if (m4 | m5 | m6 | m7) {
      i32x4 sb = *reinterpret_cast<const i32x4*>(src + base + 4);
      if (m4) {
        int slot = atomicAdd(&cursor[db[0]], 1);
        csr16[(size_t)db[0] * BS + slot] = (unsigned short)sb[0];
      }
      if (m5) {
        int slot = atomicAdd(&cursor[db[1]], 1);
        csr16[(size_t)db[1] * BS + slot] = (unsigned short)sb[1];
      }
      if (m6) {
        int slot = atomicAdd(&cursor[db[2]], 1);
        csr16[(size_t)db[2] * BS + slot] = (unsigned short)sb[2];
      }
      if (m7) {
        int slot = atomicAdd(&cursor[db[3]], 1);
        csr16[(size_t)db[3] * BS + slot] = (unsigned short)sb[3];
      }
    }
  }
  // tail (E not divisible by 8): handled by group 0's first thread
  if (blockIdx.x == 0 && threadIdx.x == 0) {
    for (int e = E8 * 8; e < E; e++) {
      int d = dst[e];
      int slot = atomicAdd(&cursor[d], 1);
      csr16[(size_t)d * BS + slot] = (unsigned short)src[e];
    }
  }
}

// agg[i][c8] = h[i][c8] + sum_{j<deg[i]} h[csr[i*BS+j]][c8]; bf16 in/out,
// f32 accumulate. 12 threads/node; 8 neighbor indices loaded per u16x8.
__global__ __launch_bounds__(TPB) void aggb_kernel(const u16x8* __restrict__ hin8,
                                                   u16x8* __restrict__ hout8,
                                                   const int* __restrict__ deg,
                                                   const unsigned short* __restrict__ csr16,
                                                   int n) {
  int t = blockIdx.x * TPB + threadIdx.x;
  if (t >= n * 12) return;
  int i = t / 12;
  int f = t - i * 12;
  const unsigned short* row = csr16 + (size_t)i * BS;
  u16x8 self = hin8[t];
  float acc[8];
#pragma unroll
  for (int k = 0; k < 8; k++) acc[k] = bf2f(self[k]);
  int e = deg[i];
  int j = 0;
  for (; j + 8 <= e; j += 8) {
    u16x8 idx = *reinterpret_cast<const u16x8*>(row + j);
    u16x8 v0 = hin8[(size_t)idx[0] * 12 + f];
    u16x8 v1 = hin8[(size_t)idx[1] * 12 + f];
    u16x8 v2 = hin8[(size_t)idx[2] * 12 + f];
    u16x8 v3 = hin8[(size_t)idx[3] * 12 + f];
    u16x8 v4 = hin8[(size_t)idx[4] * 12 + f];
    u16x8 v5 = hin8[(size_t)idx[5] * 12 + f];
    u16x8 v6 = hin8[(size_t)idx[6] * 12 + f];
    u16x8 v7 = hin8[(size_t)idx[7] * 12 + f];
#pragma unroll
    for (int k = 0; k < 8; k++)
      acc[k] += ((bf2f(v0[k]) + bf2f(v1[k])) + (bf2f(v2[k]) + bf2f(v3[k]))) +
                ((bf2f(v4[k]) + bf2f(v5[k])) + (bf2f(v6[k]) + bf2f(v7[k])));
  }
  if (j + 4 <= e) {
    int i0 = row[j], i1 = row[j + 1], i2 = row[j + 2], i3 = row[j + 3];
    u16x8 v0 = hin8[(size_t)i0 * 12 + f];
    u16x8 v1 = hin8[(size_t)i1 * 12 + f];
    u16x8 v2 = hin8[(size_t)i2 * 12 + f];
    u16x8 v3 = hin8[(size_t)i3 * 12 + f];
#pragma unroll
    for (int k = 0; k < 8; k++)
      acc[k] += (bf2f(v0[k]) + bf2f(v1[k])) + (bf2f(v2[k]) + bf2f(v3[k]));
    j += 4;
  }
  for (; j < e; j++) {
    u16x8 v = hin8[(size_t)row[j] * 12 + f];
#pragma unroll
    for (int k = 0; k < 8; k++) acc[k] += bf2f(v[k]);
  }
  u16x8 o;
#pragma unroll
  for (int k = 0; k < 8; k++) o[k] = f2bf(acc[k]);
  __builtin_nontemporal_store(o, &hout8[t]);
}

// h = relu( relu(agg@W1+B1) @ W2 + B2 ); LAST computes out = h@Wc + Bc.
// B-fragments read directly from global wt (L2-broadcast across blocks);
// LDS holds only the A/Z tile -> 13.3KB, 8 blocks/CU.
template <bool LAST>
__global__ __launch_bounds__(TPB) void mlp_mfma_kernel(
    const u16x8* __restrict__ in8, const unsigned short* __restrict__ wt1,
    const unsigned short* __restrict__ wt2, const float* __restrict__ B1,
    const float* __restrict__ B2, unsigned short* __restrict__ out,
    const float* __restrict__ Wc, const float* __restrict__ Bc,
    float* __restrict__ outf, int nrows) {
  __shared__ unsigned short A_lds[64 * LDA];   // A tile, later Z tile
  const int tid = threadIdx.x;
  const int row0 = blockIdx.x * 64;

  // stage A (already bf16), rows [row0, row0+64)
  for (int t = tid; t < 64 * 12; t += TPB) {
    int r = t / 12, c8 = t - r * 12;
    int gr = row0 + r;
    u16x8 v = {};
    if (gr < nrows) v = in8[(size_t)gr * 12 + c8];
    *reinterpret_cast<u16x8*>(&A_lds[r * LDA + 8 * c8]) = v;
  }
  __syncthreads();

  const int lane = tid & 63;
  const int w = tid >> 6;     // wave id: rows [16w, 16w+16)
  const int nl = lane & 15;   // frag row (A) / col (B,D)
  const int q = lane >> 4;    // k-quarter
  const int arow = 16 * w + nl;

  bfrag8 afrag[3];
#pragma unroll
  for (int s = 0; s < 3; s++)
    afrag[s] = *reinterpret_cast<const bfrag8*>(&A_lds[arow * LDA + 32 * s + 8 * q]);

  // GEMM1 -> relu -> Z (bf16) into this wave's own A stripe (no barrier needed)
#pragma unroll
  for (int cb = 0; cb < 6; cb++) {
    f32x4 acc = {0.f, 0.f, 0.f, 0.f};
#pragma unroll
    for (int s = 0; s < 3; s++) {
      bfrag8 bfr = *reinterpret_cast<const bfrag8*>(
          wt1 + (size_t)(16 * cb + nl) * 96 + 32 * s + 8 * q);
      acc = __builtin_amdgcn_mfma_f32_16x16x32_bf16(afrag[s], bfr, acc, 0, 0, 0);
    }
    float b = B1[16 * cb + nl];
#pragma unroll
    for (int i = 0; i < 4; i++) {
      int m = 16 * w + 4 * q + i;
      A_lds[m * LDA + 16 * cb + nl] = f2bf(fmaxf(acc[i] + b, 0.f));
    }
  }

  bfrag8 zfrag[3];
#pragma unroll
  for (int s = 0; s < 3; s++)
    zfrag[s] = *reinterpret_cast<const bfrag8*>(&A_lds[arow * LDA + 32 * s + 8 * q]);

  float oacc[40];  // LAST only: per-lane partial out[i][c], static-indexed
#pragma unroll
  for (int t2 = 0; t2 < 40; t2++) oacc[t2] = 0.f;

#pragma unroll
  for (int cb = 0; cb < 6; cb++) {
    f32x4 acc = {0.f, 0.f, 0.f, 0.f};
#pragma unroll
    for (int s = 0; s < 3; s++) {
      bfrag8 bfr = *reinterpret_cast<const bfrag8*>(
          wt2 + (size_t)(16 * cb + nl) * 96 + 32 * s + 8 * q);
      acc = __builtin_amdgcn_mfma_f32_16x16x32_bf16(zfrag[s], bfr, acc, 0, 0, 0);
    }
    float b = B2[16 * cb + nl];
#pragma unroll
    for (int i = 0; i < 4; i++) {
      float hv = fmaxf(acc[i] + b, 0.f);
      if (!LAST) {
        int m = 16 * w + 4 * q + i;
        int gr = row0 + m;
        if (gr < nrows)
          __builtin_nontemporal_store(f2bf(hv), &out[(size_t)gr * 96 + 16 * cb + nl]);
      } else {
#pragma unroll
        for (int c = 0; c < 10; c++)
          oacc[i * 10 + c] += hv * Wc[(16 * cb + nl) * 10 + c];
      }
    }
  }

  if (LAST) {
    // reduce over the 16 nl-lanes within each q-group
#pragma unroll
    for (int m = 1; m < 16; m <<= 1) {
#pragma unroll
      for (int t2 = 0; t2 < 40; t2++) oacc[t2] += __shfl_xor(oacc[t2], m, 64);
    }
#pragma unroll
    for (int i = 0; i < 4; i++) {
      int gr = row0 + 16 * w + 4 * q + i;
      if (gr < nrows && nl < 10) {
        float v = 0.f;
#pragma unroll
        for (int c = 0; c < 10; c++)
          if (nl == c) v = oacc[i * 10 + c];
        __builtin_nontemporal_store(v + Bc[nl], &outf[(size_t)gr * 10 + nl]);
      }
    }
  }
}

extern "C" void kernel_launch(void* const* d_in, const int* in_sizes, int n_in,
                              void* d_out, int out_size, void* d_ws, size_t ws_size,
                              hipStream_t stream) {
  const float* x  = (const float*)d_in[0];
  const int*   ei = (const int*)d_in[1];
  const float* W1 = (const float*)d_in[2];
  const float* B1 = (const float*)d_in[3];
  const float* W2 = (const float*)d_in[4];
  const float* B2 = (const float*)d_in[5];
  const float* Wc = (const float*)d_in[6];
  const float* Bc = (const float*)d_in[7];
  float* out = (float*)d_out;

  const int N = in_sizes[0] / 96;
  const int E = in_sizes[1] / 2;
  const int* src = ei;       // edge_index[0]
  const int* dst = ei + E;   // edge_index[1]

  unsigned short* hbuf   = (unsigned short*)d_ws;        // N*96 bf16
  unsigned short* aggbuf = hbuf + (size_t)N * 96;        // N*96 bf16
  int* cursor = (int*)(aggbuf + (size_t)N * 96);         // N int (deg after fill)
  unsigned short* csr16 = (unsigned short*)(cursor + N); // N*BS u16
  unsigned short* wt    = csr16 + (size_t)N * BS;        // 6*9216 u16

  const int total8 = N * 12;
  const int prep_jobs = N + 6 * 9216 + total8;
  prep_kernel<<<(prep_jobs + TPB - 1) / TPB, TPB, 0, stream>>>(
      cursor, N, W1, W2, wt, (const float4*)x, (u16x8*)hbuf, total8);

  fill_kernel<<<2048, TPB, 0, stream>>>(src, dst, cursor, csr16, N, E);

  for (int l = 0; l < 3; l++) {
    aggb_kernel<<<((N * 12) + TPB - 1) / TPB, TPB, 0, stream>>>(
        (const u16x8*)hbuf, (u16x8*)aggbuf, cursor, csr16, N);
    const unsigned short* wt1 = wt + (size_t)(l * 2) * 9216;
    const unsigned short* wt2 = wt + (size_t)(l * 2 + 1) * 9216;
    const float* b1 = B1 + (size_t)l * 96;
    const float* b2 = B2 + (size_t)l * 96;
    if (l < 2)
      mlp_mfma_kernel<false><<<(N + 63) / 64, TPB, 0, stream>>>(
          (const u16x8*)aggbuf, wt1, wt2, b1, b2, hbuf, Wc, Bc, out, N);
    else
      mlp_mfma_kernel<true><<<(N + 63) / 64, TPB, 0, stream>>>(
          (const u16x8*)aggbuf, wt1, wt2, b1, b2, hbuf, Wc, Bc, out, N);
  }
}